// Round 6
// baseline (197.674 us; speedup 1.0000x reference)
//
#include <hip/hip_runtime.h>
#include <math.h>

#define N_PTS 8192
#define KFULL 40
#define KNB 20
#define NBK 1024
#define CAP 384
#define GR 16

typedef unsigned short u16;
typedef unsigned int u32;
typedef unsigned long long u64;
typedef __attribute__((ext_vector_type(8))) short bf16x8;
typedef __attribute__((ext_vector_type(4))) float f32x4;

__device__ __forceinline__ u16 f2b(float v) {  // RNE float->bf16 bits
  u32 u = __float_as_uint(v);
  return (u16)((u + 0x7FFFu + ((u >> 16) & 1u)) >> 16);
}
__device__ __forceinline__ u32 pk2(float a, float b) {
  return (u32)f2b(a) | ((u32)f2b(b) << 16);
}
__device__ __forceinline__ u32 dmap(float d) {  // order-preserving float->u32
  u32 b = __float_as_uint(d);
  return b ^ ((u32)(((int)b) >> 31) | 0x80000000u);
}
__device__ __forceinline__ float inv_edge(int b) {  // upper-edge float of bucket b
  if (b >= 1022) return 3.4e38f;
  const u32 m = (((u32)(b + 1)) << 22) - 1u;
  if (m < 0x80000000u) return 0.f;
  return __uint_as_float(m - 0x80000000u);
}
__device__ __forceinline__ int cellc(float x) {  // shared cell map (16 over [-5,5])
  int c = (int)floorf((x + 5.0f) * 1.6f);
  return c < 0 ? 0 : (c > 15 ? 15 : c);
}
__device__ __forceinline__ void maxu4(const uint4 v, float m[8]) {
  m[0] = fmaxf(m[0], __uint_as_float(v.x << 16));
  m[1] = fmaxf(m[1], __uint_as_float(v.x & 0xFFFF0000u));
  m[2] = fmaxf(m[2], __uint_as_float(v.y << 16));
  m[3] = fmaxf(m[3], __uint_as_float(v.y & 0xFFFF0000u));
  m[4] = fmaxf(m[4], __uint_as_float(v.z << 16));
  m[5] = fmaxf(m[5], __uint_as_float(v.z & 0xFFFF0000u));
  m[6] = fmaxf(m[6], __uint_as_float(v.w << 16));
  m[7] = fmaxf(m[7], __uint_as_float(v.w & 0xFFFF0000u));
}
__device__ __forceinline__ void unp4(const uint4 v, float p[8]) {
  p[0] = __uint_as_float(v.x << 16);
  p[1] = __uint_as_float(v.x & 0xFFFF0000u);
  p[2] = __uint_as_float(v.y << 16);
  p[3] = __uint_as_float(v.y & 0xFFFF0000u);
  p[4] = __uint_as_float(v.z << 16);
  p[5] = __uint_as_float(v.z & 0xFFFF0000u);
  p[6] = __uint_as_float(v.w << 16);
  p[7] = __uint_as_float(v.w & 0xFFFF0000u);
}

typedef const __attribute__((address_space(1))) unsigned int* gas_p;
typedef __attribute__((address_space(3))) unsigned int* las_p;
__device__ __forceinline__ void gll16(const void* g, void* l) {
  __builtin_amdgcn_global_load_lds((gas_p)g, (las_p)l, 16, 0, 0);
}

// ---------------------------------------------------------------------------
// Cell build: count -> scan -> scatter (counting sort by 16^3 cell id)
// ---------------------------------------------------------------------------
__global__ __launch_bounds__(512) void cell_count_kernel(const float4* __restrict__ pos4,
                                                         int* __restrict__ cellcnt) {
  const int j = blockIdx.x * 512 + threadIdx.x;
  const float4 p = pos4[j];
  const int cid = (cellc(p.x) << 8) | (cellc(p.y) << 4) | cellc(p.z);
  atomicAdd(&cellcnt[cid], 1);
}

__global__ __launch_bounds__(1024) void cell_scan_kernel(const int* __restrict__ cnt,
                                                         int* __restrict__ start) {
  __shared__ int wsum[16];
  const int t = threadIdx.x, lane = t & 63, w = t >> 6;
  const int c0 = cnt[t * 4], c1 = cnt[t * 4 + 1], c2 = cnt[t * 4 + 2], c3 = cnt[t * 4 + 3];
  const int s = c0 + c1 + c2 + c3;
  int inc = s;
#pragma unroll
  for (int off = 1; off < 64; off <<= 1) {
    const int u = __shfl_up(inc, off);
    if (lane >= off) inc += u;
  }
  if (lane == 63) wsum[w] = inc;
  __syncthreads();
  int wpre = 0;
  for (int k = 0; k < w; ++k) wpre += wsum[k];
  const int excl = wpre + inc - s;
  start[t * 4] = excl;
  start[t * 4 + 1] = excl + c0;
  start[t * 4 + 2] = excl + c0 + c1;
  start[t * 4 + 3] = excl + c0 + c1 + c2;
  if (t == 1023) start[4096] = excl + s;
}

__global__ __launch_bounds__(512) void cell_scatter_kernel(
    const float4* __restrict__ pos4, const int* __restrict__ cellstart,
    int* __restrict__ fill, float4* __restrict__ pos4s, int* __restrict__ perm) {
  const int j = blockIdx.x * 512 + threadIdx.x;
  const float4 p = pos4[j];
  const int cid = (cellc(p.x) << 8) | (cellc(p.y) << 4) | cellc(p.z);
  const int slot = cellstart[cid] + atomicAdd(&fill[cid], 1);
  pos4s[slot] = p;
  perm[slot] = j;
}

// ---------------------------------------------------------------------------
// wave-local cutoff scan: bucket where cumulative count reaches 41.
// ---------------------------------------------------------------------------
__device__ __forceinline__ int scan_cut_wave(const u32* H, int lane) {
  const int base = lane * 16;
  u32 lsum = 0;
#pragma unroll
  for (int k = 0; k < 16; ++k) lsum += H[base + k];
  u32 inc = lsum;
#pragma unroll
  for (int off = 1; off < 64; off <<= 1) {
    const u32 u = __shfl_up(inc, off);
    if (lane >= off) inc += u;
  }
  const u32 excl = inc - lsum;
  int cut = -1;
  if (excl < 41u && inc >= 41u) {
    u32 cum = excl;
    for (int k = 0; k < 16; ++k) {
      cum += H[base + k];
      if (cum >= 41u) { cut = base + k; break; }
    }
  }
  const u64 mask = __ballot(cut >= 0);
  if (mask == 0ull) return NBK - 1;  // fallback: scan everything (exact, slow)
  const int src = __ffsll((long long)mask) - 1;
  return __shfl(cut, src);
}

// ---------------------------------------------------------------------------
// kNN v6: one wave per sorted query. Phase 0: stride-8 subsample bound.
// Pass 1: histogram over cells in box(R0) -> exact cutoff. Pass 2: compact
// over box(R1). Rank-sort keys (dist | orig idx); self = rank 0, dropped.
// ---------------------------------------------------------------------------
__global__ __launch_bounds__(512) void knn_kernel(const float4* __restrict__ pos4s,
                                                  const int* __restrict__ perm,
                                                  const int* __restrict__ cellstart,
                                                  int* __restrict__ idx_out) {
  __shared__ __align__(16) u32 hist[8][NBK];  // 32 KB; cand aliases
  u64 (*cand)[CAP] = (u64(*)[CAP])hist;       // 8*384*8 = 24 KB
  __shared__ int s_cnt[8];

  const int t = threadIdx.x, w = t >> 6, lane = t & 63;
  const int qslot = blockIdx.x * 8 + w;
  const float4 q = pos4s[qslot];
  const float ax = -2.0f * q.x, ay = -2.0f * q.y, az = -2.0f * q.z, aw = q.w;

  for (int b = lane; b < NBK; b += 64) hist[w][b] = 0;
  if (lane == 0) s_cnt[w] = 0;
  __syncthreads();

  // ---- phase 0: stride-8 subsample of sorted points (valid subset bound) ----
#pragma unroll 4
  for (int j = lane; j < 1024; j += 64) {
    const float4 p = pos4s[j * 8];
    const float d = fmaf(ax, p.x, fmaf(ay, p.y, fmaf(az, p.z, aw + p.w)));
    atomicAdd(&hist[w][dmap(d) >> 22], 1u);
  }
  __syncthreads();
  const int bc0 = scan_cut_wave(hist[w], lane);
  const float R2a = fmaxf(inv_edge(bc0), 0.f);
  __syncthreads();
  for (int b = lane; b < NBK; b += 64) hist[w][b] = 0;
  __syncthreads();

  // ---- pass 1: refine cutoff over box(R0) ----
  {
    const float R = sqrtf(R2a) * 1.0001f + 1e-6f;
    const int cxlo = cellc(q.x - R), cxhi = cellc(q.x + R);
    const int cylo = cellc(q.y - R), cyhi = cellc(q.y + R);
    const int czlo = cellc(q.z - R), czhi = cellc(q.z + R);
    for (int cx = cxlo; cx <= cxhi; ++cx)
      for (int cy = cylo; cy <= cyhi; ++cy) {
        const int base = (cx << 8) | (cy << 4);
        const int js = cellstart[base | czlo];
        const int je = cellstart[(base | czhi) + 1];
        for (int j = js + lane; j < je; j += 64) {
          const float4 p = pos4s[j];
          const float d = fmaf(ax, p.x, fmaf(ay, p.y, fmaf(az, p.z, aw + p.w)));
          if (d <= R2a) atomicAdd(&hist[w][dmap(d) >> 22], 1u);
        }
      }
  }
  __syncthreads();
  const int bc1 = scan_cut_wave(hist[w], lane);
  const float R2b = fmaxf(inv_edge(bc1), 0.f);
  __syncthreads();  // required: cand aliases hist across waves

  // ---- pass 2: compact candidates over box(R1) ----
  {
    const float R = sqrtf(R2b) * 1.0001f + 1e-6f;
    const int cxlo = cellc(q.x - R), cxhi = cellc(q.x + R);
    const int cylo = cellc(q.y - R), cyhi = cellc(q.y + R);
    const int czlo = cellc(q.z - R), czhi = cellc(q.z + R);
    for (int cx = cxlo; cx <= cxhi; ++cx)
      for (int cy = cylo; cy <= cyhi; ++cy) {
        const int base = (cx << 8) | (cy << 4);
        const int js = cellstart[base | czlo];
        const int je = cellstart[(base | czhi) + 1];
        for (int j = js + lane; j < je; j += 64) {
          const float4 p = pos4s[j];
          const float d = fmaf(ax, p.x, fmaf(ay, p.y, fmaf(az, p.z, aw + p.w)));
          if (d <= R2b) {
            const int slot = atomicAdd(&s_cnt[w], 1);
            if (slot < CAP)
              cand[w][slot] = ((u64)dmap(d) << 13) | (u64)perm[j];
          }
        }
      }
  }
  __syncthreads();

  // ---- rank sort (self excluded as rank 0) ----
  const int cnt = s_cnt[w] < CAP ? s_cnt[w] : CAP;
  const int orig_q = perm[qslot];
  for (int c0 = lane; c0 < cnt; c0 += 64) {
    const u64 my = cand[w][c0];
    int rank = 0;
    for (int c = 0; c < cnt; ++c) rank += (cand[w][c] < my) ? 1 : 0;
    if (rank >= 1 && rank <= KFULL)
      idx_out[orig_q * KFULL + (rank - 1)] = (int)(my & 0x1FFFull);
  }
}

// ---------------------------------------------------------------------------
// Weight convert+transpose body: dst[r][k] = f2b(src[(part*128+k)*ncols+col])
// ---------------------------------------------------------------------------
__device__ __forceinline__ void wcvt_body(const float* __restrict__ src,
                                          u16* __restrict__ dst, int ncols,
                                          int rows_per_tensor, int elems_per_tensor,
                                          int rg, int k) {
  const int li = rg / rows_per_tensor;
  const int r = rg % rows_per_tensor;
  const float* s = src + (size_t)li * elems_per_tensor;
  u16* d = dst + (size_t)li * elems_per_tensor;
  const int part = r / ncols, col = r % ncols;
  d[(size_t)r * 128 + k] = f2b(s[(size_t)(part * 128 + k) * ncols + col]);
}

// ---------------------------------------------------------------------------
// Fused preamble: lift | Wg cvt | Wu cvt | Wr1 cvt | pos4 | zero cell counters
// ---------------------------------------------------------------------------
__global__ __launch_bounds__(128) void prep_kernel(
    const float* __restrict__ x, const float* __restrict__ W0,
    const float* __restrict__ b0, const float* __restrict__ Wg,
    const float* __restrict__ Wu, const float* __restrict__ Wr1,
    float* __restrict__ Aout, u16* __restrict__ Pout, u16* __restrict__ Wgb,
    u16* __restrict__ Wub, u16* __restrict__ Wr1b, float4* __restrict__ pos4,
    int* __restrict__ cellcnt) {
  const int b = blockIdx.x, t = threadIdx.x;
  if (b < 8192) {  // lift: A = x@W0[0:3]+b0 (f32), P = x@W0[3:6] (bf16)
    const float px = x[b * 3 + 0], py = x[b * 3 + 1], pz = x[b * 3 + 2];
    const float a = b0[t] + px * W0[t] + py * W0[128 + t] + pz * W0[256 + t];
    const float p = px * W0[384 + t] + py * W0[512 + t] + pz * W0[640 + t];
    Aout[(size_t)b * 128 + t] = a;
    Pout[(size_t)b * 128 + t] = f2b(p);
  } else if (b < 9216) {
    wcvt_body(Wg, Wgb, 128, 256, 256 * 128, b - 8192, t);
  } else if (b < 10240) {
    wcvt_body(Wu, Wub, 512, 1024, 1024 * 128, b - 9216, t);
  } else if (b < 10368) {
    wcvt_body(Wr1, Wr1b, 128, 128, 128 * 128, b - 10240, t);
  } else if (b < 10432) {
    const int j = (b - 10368) * 128 + t;
    const float px = x[j * 3 + 0], py = x[j * 3 + 1], pz = x[j * 3 + 2];
    pos4[j] = make_float4(px, py, pz, px * px + py * py + pz * pz);
  } else {
    cellcnt[(b - 10432) * 128 + t] = 0;  // zeroes cellcnt[4096] + fill[4096]
  }
}

// ---------------------------------------------------------------------------
// bf16 MFMA GEMM, K=128, BM=128, BN=64. Epilogue splits per-group cols into
// A (f32, +bias, opt act) and P (bf16).
// ---------------------------------------------------------------------------
__global__ __launch_bounds__(256) void gemm_mfma_kernel(
    const u16* __restrict__ Ain, const u16* __restrict__ Wt,
    const float* __restrict__ bias, int GA, int span_shift, int nAtot, int nPtot,
    float slope, int use_act, float* __restrict__ Aout, u16* __restrict__ Pout) {
  __shared__ __align__(16) u16 Al[128 * 128];
  __shared__ __align__(16) u16 Bl[64 * 128];
  const int bm = blockIdx.x * 128;
  const int bn = blockIdx.y * 64;
  const int tid = threadIdx.x;

#pragma unroll
  for (int it = 0; it < 8; ++it) {
    const int g = it * 256 + tid;
    const int row = g >> 4, cc = g & 15;
    const int sc = cc ^ (row & 7);
    gll16(Ain + (size_t)(bm + row) * 128 + sc * 8, &Al[g * 8]);
  }
#pragma unroll
  for (int it = 0; it < 4; ++it) {
    const int g = it * 256 + tid;
    const int row = g >> 4, cc = g & 15;
    const int sc = cc ^ (row & 7);
    gll16(Wt + (size_t)(bn + row) * 128 + sc * 8, &Bl[g * 8]);
  }
  __syncthreads();

  const int wv = tid >> 6, lane = tid & 63;
  const int wm = wv & 1, wn = wv >> 1;
  const int lr = lane & 15, lk = lane >> 4;

  bf16x8 a[4][4], b[2][4];
  f32x4 acc[4][2];
#pragma unroll
  for (int m = 0; m < 4; ++m)
#pragma unroll
    for (int n = 0; n < 2; ++n) acc[m][n] = (f32x4){0.f, 0.f, 0.f, 0.f};

#pragma unroll
  for (int m = 0; m < 4; ++m) {
    const int row = wm * 64 + m * 16 + lr;
#pragma unroll
    for (int ks = 0; ks < 4; ++ks) {
      const int c = ks * 4 + lk;
      a[m][ks] = *(const bf16x8*)&Al[row * 128 + (c ^ (row & 7)) * 8];
    }
  }
#pragma unroll
  for (int n = 0; n < 2; ++n) {
    const int col = wn * 32 + n * 16 + lr;
#pragma unroll
    for (int ks = 0; ks < 4; ++ks) {
      const int c = ks * 4 + lk;
      b[n][ks] = *(const bf16x8*)&Bl[col * 128 + (c ^ (col & 7)) * 8];
    }
  }

#pragma unroll
  for (int ks = 0; ks < 4; ++ks)
#pragma unroll
    for (int m = 0; m < 4; ++m)
#pragma unroll
      for (int n = 0; n < 2; ++n)
        acc[m][n] = __builtin_amdgcn_mfma_f32_16x16x32_bf16(a[m][ks], b[n][ks],
                                                            acc[m][n], 0, 0, 0);

  const int span = 1 << span_shift;
  const int GP = span - GA;
#pragma unroll
  for (int n = 0; n < 2; ++n) {
    const int col = bn + wn * 32 + n * 16 + lr;
    const int g = col >> span_shift;
    const int wi = col & (span - 1);
    const bool isA = wi < GA;
    const float bv = isA ? bias[g * GA + wi] : 0.f;
#pragma unroll
    for (int m = 0; m < 4; ++m) {
      const int row0 = bm + wm * 64 + m * 16 + lk * 4;
#pragma unroll
      for (int r = 0; r < 4; ++r) {
        float v = acc[m][n][r] + bv;
        if (isA) {
          if (use_act) v = v > 0.f ? v : v * slope;
          Aout[(size_t)(row0 + r) * nAtot + g * GA + wi] = v;
        } else {
          Pout[(size_t)(row0 + r) * nPtot + g * GP + (wi - GA)] = f2b(v);
        }
      }
    }
  }
}

// ---------------------------------------------------------------------------
// Single-branch gather-max: out = LR(A - P_self + max_j P[nbr_j], 0.2).
// ---------------------------------------------------------------------------
__global__ __launch_bounds__(256) void gather_one_kernel(
    const float* __restrict__ A, const u16* __restrict__ P,
    const int* __restrict__ idx, int C, int dil, float* __restrict__ outf,
    u16* __restrict__ outb) {
  const int t = threadIdx.x;
  const int i = blockIdx.x * 16 + (t >> 4);
  const int c = blockIdx.y * 128 + (t & 15) * 8;
  float m[8];
#pragma unroll
  for (int k = 0; k < 8; ++k) m[k] = -INFINITY;
  const int ib = i * KFULL;
#pragma unroll
  for (int j = 0; j < KNB; ++j) {
    const int n = idx[ib + j * dil] & (N_PTS - 1);
    maxu4(*(const uint4*)&P[(size_t)n * C + c], m);
  }
  float pv[8];
  unp4(*(const uint4*)&P[(size_t)i * C + c], pv);
  const float4 a0 = *(const float4*)&A[(size_t)i * C + c];
  const float4 a1 = *(const float4*)&A[(size_t)i * C + c + 4];
  const float av[8] = {a0.x, a0.y, a0.z, a0.w, a1.x, a1.y, a1.z, a1.w};
  float v[8];
#pragma unroll
  for (int k = 0; k < 8; ++k) {
    const float x = av[k] - pv[k] + m[k];
    v[k] = x > 0.f ? x : 0.2f * x;
  }
  if (outf) {
    *(float4*)&outf[(size_t)i * C + c] = make_float4(v[0], v[1], v[2], v[3]);
    *(float4*)&outf[(size_t)i * C + c + 4] = make_float4(v[4], v[5], v[6], v[7]);
  }
  if (outb) {
    uint4 pb = {pk2(v[0], v[1]), pk2(v[2], v[3]), pk2(v[4], v[5]), pk2(v[6], v[7])};
    *(uint4*)&outb[(size_t)i * C + c] = pb;
  }
}

// ---------------------------------------------------------------------------
// Fused inception pair: h += 0.5*(LR(A0-P0+max_dil1 P0) + LR(A1-P1+max_dil2 P1))
// ---------------------------------------------------------------------------
__global__ __launch_bounds__(256) void gather_pair_kernel(
    const float* __restrict__ Ap, const u16* __restrict__ Pp,
    const int* __restrict__ idx, float* __restrict__ h, u16* __restrict__ hb) {
  const int t = threadIdx.x;
  const int i = blockIdx.x * 16 + (t >> 4);
  const int c = (t & 15) * 8;
  float m1[8], m2[8];
#pragma unroll
  for (int k = 0; k < 8; ++k) { m1[k] = -INFINITY; m2[k] = -INFINITY; }
  const int ib = i * KFULL;
#pragma unroll
  for (int j = 0; j < KNB; ++j) {
    const int n1 = idx[ib + j] & (N_PTS - 1);
    maxu4(*(const uint4*)&Pp[(size_t)n1 * 256 + c], m1);
    const int n2 = idx[ib + 2 * j] & (N_PTS - 1);
    maxu4(*(const uint4*)&Pp[(size_t)n2 * 256 + 128 + c], m2);
  }
  float p0[8], p1[8];
  unp4(*(const uint4*)&Pp[(size_t)i * 256 + c], p0);
  unp4(*(const uint4*)&Pp[(size_t)i * 256 + 128 + c], p1);
  const float4 a00 = *(const float4*)&Ap[(size_t)i * 256 + c];
  const float4 a01 = *(const float4*)&Ap[(size_t)i * 256 + c + 4];
  const float4 a10 = *(const float4*)&Ap[(size_t)i * 256 + 128 + c];
  const float4 a11 = *(const float4*)&Ap[(size_t)i * 256 + 128 + c + 4];
  const float av0[8] = {a00.x, a00.y, a00.z, a00.w, a01.x, a01.y, a01.z, a01.w};
  const float av1[8] = {a10.x, a10.y, a10.z, a10.w, a11.x, a11.y, a11.z, a11.w};
  const float4 h0 = *(const float4*)&h[(size_t)i * 128 + c];
  const float4 h1 = *(const float4*)&h[(size_t)i * 128 + c + 4];
  const float hv[8] = {h0.x, h0.y, h0.z, h0.w, h1.x, h1.y, h1.z, h1.w};
  float v[8];
#pragma unroll
  for (int k = 0; k < 8; ++k) {
    float x1 = av0[k] - p0[k] + m1[k];
    x1 = x1 > 0.f ? x1 : 0.2f * x1;
    float x2 = av1[k] - p1[k] + m2[k];
    x2 = x2 > 0.f ? x2 : 0.2f * x2;
    v[k] = hv[k] + 0.5f * (x1 + x2);
  }
  *(float4*)&h[(size_t)i * 128 + c] = make_float4(v[0], v[1], v[2], v[3]);
  *(float4*)&h[(size_t)i * 128 + c + 4] = make_float4(v[4], v[5], v[6], v[7]);
  uint4 pb = {pk2(v[0], v[1]), pk2(v[2], v[3]), pk2(v[4], v[5]), pk2(v[6], v[7])};
  *(uint4*)&hb[(size_t)i * 128 + c] = pb;
}

// ---------------------------------------------------------------------------
// Final projection: q = T @ Wr2 + br2   (T: [32768,128], Wr2: [128,3])
// ---------------------------------------------------------------------------
__global__ __launch_bounds__(128) void recon2_kernel(const float* __restrict__ T,
                                                     const float* __restrict__ Wr2,
                                                     const float* __restrict__ br2,
                                                     float* __restrict__ out) {
  __shared__ float tile[32][129];
  __shared__ float w2[384];
  const int tid = threadIdx.x;
  const int r0 = blockIdx.x * 32;
  w2[tid] = Wr2[tid];
  w2[tid + 128] = Wr2[tid + 128];
  w2[tid + 256] = Wr2[tid + 256];
  for (int s = 0; s < 32; ++s) tile[s][tid] = T[(size_t)(r0 + s) * 128 + tid];
  __syncthreads();
  if (tid < 96) {
    const int r = tid / 3, n = tid % 3;
    float acc = br2[n];
#pragma unroll
    for (int k = 0; k < 128; ++k) acc = fmaf(tile[r][k], w2[k * 3 + n], acc);
    out[(size_t)(r0 + r) * 3 + n] = acc;
  }
}

// ---------------------------------------------------------------------------
extern "C" void kernel_launch(void* const* d_in, const int* in_sizes, int n_in,
                              void* d_out, int out_size, void* d_ws, size_t ws_size,
                              hipStream_t stream) {
  const float* x = (const float*)d_in[0];
  const float* W0 = (const float*)d_in[1];
  const float* b0 = (const float*)d_in[2];
  const float* Wg = (const float*)d_in[3];
  const float* bg = (const float*)d_in[4];
  const float* Wu = (const float*)d_in[5];
  const float* bu = (const float*)d_in[6];
  const float* Wr1 = (const float*)d_in[7];
  const float* br1 = (const float*)d_in[8];
  const float* Wr2 = (const float*)d_in[9];
  const float* br2 = (const float*)d_in[10];
  float* out = (float*)d_out;

  char* w = (char*)d_ws;
  int* idx = (int*)(w + 0);               // 1,310,720
  float4* pos4 = (float4*)(w + 1310720);  // 131,072
  float* h = (float*)(w + 1441792);       // 4 MB
  u16* hb = (u16*)(w + 5636096);          // 2 MB
  float* Apair = (float*)(w + 7733248);   // 8 MB   (Ub aliases)
  u16* Ppair = (u16*)(w + 16121856);      // 4 MB
  u16* Wgb = (u16*)(w + 20316160);        // 256 KB
  u16* Wub = (u16*)(w + 20578304);        // 256 KB
  u16* Wr1b = (u16*)(w + 20840448);       // 32 KB
  float* Abig = (float*)(w + 20873216);   // 16 MB  (T aliases)
  u16* Pbig = (u16*)(w + 37650432);       // 8 MB
  float4* pos4s = (float4*)(w + 46039040);  // 128 KB (cell-sorted points)
  int* perm = (int*)(w + 46170112);         // 32 KB
  int* cellstart = (int*)(w + 46202880);    // 16.4 KB (4097 ints)
  int* cellcnt = (int*)(w + 46219520);      // 16 KB
  int* fill = (int*)(w + 46235904);         // 16 KB (contiguous after cellcnt)
  u16* Ub = (u16*)Apair;                  // Apair dead when Ub produced
  float* T = Abig;                        // Abig dead when T produced

  // fused preamble: lift | Wg cvt | Wu cvt | Wr1 cvt | pos4 | zero counters
  prep_kernel<<<10496, 128, 0, stream>>>(x, W0, b0, Wg, Wu, Wr1, Abig, Pbig, Wgb,
                                         Wub, Wr1b, pos4, cellcnt);

  // cell build + kNN
  cell_count_kernel<<<16, 512, 0, stream>>>(pos4, cellcnt);
  cell_scan_kernel<<<1, 1024, 0, stream>>>(cellcnt, cellstart);
  cell_scatter_kernel<<<16, 512, 0, stream>>>(pos4, cellstart, fill, pos4s, perm);
  knn_kernel<<<1024, 512, 0, stream>>>(pos4s, perm, cellstart, idx);

  gather_one_kernel<<<dim3(512, 1), 256, 0, stream>>>(Abig, Pbig, idx, 128, 1, h, hb);

  // 2 inception blocks, each = one pair-GEMM (N=512) + one fused gather
  for (int blk = 0; blk < 2; ++blk) {
    const int li = blk * 2;
    gemm_mfma_kernel<<<dim3(64, 8), 256, 0, stream>>>(
        hb, Wgb + (size_t)li * 256 * 128, bg + li * 128, 128, 8, 256, 256, 0.f, 0,
        Apair, Ppair);
    gather_pair_kernel<<<512, 256, 0, stream>>>(Apair, Ppair, idx, h, hb);
  }

  // NodeShuffle upsampler (r*C = 512), column-blocked gather
  gemm_mfma_kernel<<<dim3(64, 16), 256, 0, stream>>>(hb, Wub, bu, 512, 10, 512, 512,
                                                     0.f, 0, Abig, Pbig);
  gather_one_kernel<<<dim3(512, 4), 256, 0, stream>>>(Abig, Pbig, idx, 512, 1,
                                                      (float*)nullptr, Ub);

  // reconstructor MLP
  gemm_mfma_kernel<<<dim3(256, 2), 256, 0, stream>>>(Ub, Wr1b, br1, 128, 7, 128, 128,
                                                     0.01f, 1, T, (u16*)nullptr);
  recon2_kernel<<<1024, 128, 0, stream>>>(T, Wr2, br2, out);
}